// Round 9
// baseline (173.409 us; speedup 1.0000x reference)
//
#include <hip/hip_runtime.h>
#include <float.h>

typedef unsigned long long u64;
typedef unsigned int u32;
typedef unsigned short u16;

#define NPTS 4096
#define CDIM 64
#define BATCH 8
#define KSEL 20

// ---- small layout (r8-validated, ws >= 19.56 MB) ----
#define OFF_Y1 0
#define OFF_XTL (BATCH * NPTS * CDIM / 2)       // xth [0,4MB), xtl [4,8MB)
#define OFF_Y2 (BATCH * NPTS * 64)              // [8,16MB): cand (small) / y2
#define S_OFF_SQ (2 * BATCH * NPTS * 64)
#define S_OFF_WT (S_OFF_SQ + BATCH * NPTS)
#define S_OFF_KNN (S_OFF_WT + 64 * 128)
// ---- big layout (8-chunk cand = 16MB at [8,24MB), ws >= 26.66 MB) ----
#define B_OFF_SQ (6 * BATCH * NPTS * 32)        // 6,291,456 floats = 24MB
#define B_OFF_WT (B_OFF_SQ + BATCH * NPTS)
#define B_OFF_KNN (B_OFF_WT + 64 * 128)
#define B_NEED_BYTES ((size_t)(B_OFF_KNN + BATCH * NPTS * KSEL) * 4)

typedef __attribute__((ext_vector_type(8))) short short8v;   // 8 bf16 (4 VGPR)
typedef __attribute__((ext_vector_type(16))) float float16v; // MFMA 32x32 acc

#define MFMA32(a, b, c) __builtin_amdgcn_mfma_f32_32x32x16_bf16(a, b, c, 0, 0, 0)

__device__ __forceinline__ u32 ordf(float f) {
    u32 u = __float_as_uint(f);
    return (u >> 31) ? ~u : (u | 0x80000000u);
}
__device__ __forceinline__ u32 umaxu(u32 a, u32 b) { return a > b ? a : b; }
__device__ __forceinline__ u32 uminu(u32 a, u32 b) { return a < b ? a : b; }

__device__ __forceinline__ void load_lds_16(const void* g, void* l) {
    __builtin_amdgcn_global_load_lds(
        (const __attribute__((address_space(1))) unsigned int*)g,
        (__attribute__((address_space(3))) unsigned int*)l, 16, 0, 0);
}

#define CE(i, j) { u32 a_ = c[i], b_ = c[j]; c[i] = umaxu(a_, b_); c[j] = uminu(a_, b_); }

// Batcher odd-even merge sort, 16 u32 keys, descending. 63 CEs.
__device__ __forceinline__ void sort16_desc(u32 (&c)[16]) {
    CE(0,1) CE(2,3) CE(4,5) CE(6,7) CE(8,9) CE(10,11) CE(12,13) CE(14,15)
    CE(0,2) CE(1,3) CE(4,6) CE(5,7) CE(8,10) CE(9,11) CE(12,14) CE(13,15)
    CE(1,2) CE(5,6) CE(9,10) CE(13,14)
    CE(0,4) CE(1,5) CE(2,6) CE(3,7) CE(8,12) CE(9,13) CE(10,14) CE(11,15)
    CE(2,4) CE(3,5) CE(10,12) CE(11,13)
    CE(1,2) CE(3,4) CE(5,6) CE(9,10) CE(11,12) CE(13,14)
    CE(0,8) CE(1,9) CE(2,10) CE(3,11) CE(4,12) CE(5,13) CE(6,14) CE(7,15)
    CE(4,8) CE(5,9) CE(6,10) CE(7,11)
    CE(2,4) CE(3,5) CE(6,8) CE(7,9) CE(10,12) CE(11,13)
    CE(1,2) CE(3,4) CE(5,6) CE(7,8) CE(9,10) CE(11,12) CE(13,14)
}
#undef CE

// L (desc,16) <- top-16 of L ∪ c (desc,16): max-half + bitonic merge
__device__ __forceinline__ void merge_into16(u32 (&L)[16], const u32 (&c)[16]) {
#pragma unroll
    for (int i = 0; i < 16; i++) L[i] = umaxu(L[i], c[15 - i]);
#pragma unroll
    for (int j = 8; j >= 1; j >>= 1)
#pragma unroll
        for (int i = 0; i < 16; i++)
            if ((i & j) == 0) {
                int p = i | j;
                u32 a = L[i], b = L[p];
                L[i] = umaxu(a, b);
                L[p] = uminu(a, b);
            }
}

// ---------------------------------------------------------------------------
// k0: W (64 x 128) -> Wt[c][o'] (64 x 128): o'<64: W1^T ; o'>=64: (W2-W1)^T
// ---------------------------------------------------------------------------
__global__ void k0_wt(const float* __restrict__ W, float* __restrict__ Wt) {
    int f = blockIdx.x * 256 + threadIdx.x;
    if (f >= 64 * 128) return;
    int c = f >> 7, o = f & 127;
    float v;
    if (o < 64) {
        v = W[o * 128 + c];
    } else {
        int oo = o - 64;
        v = W[oo * 128 + 64 + c] - W[oo * 128 + c];
    }
    Wt[f] = v;
}

// ---------------------------------------------------------------------------
// p1: transpose x[b][c][n] -> xtf (fp32, in d_out), xth/xtl (bf16 hi/lo, RNE),
// sq[n]. (validated rounds 2-8)
// ---------------------------------------------------------------------------
__global__ __launch_bounds__(256) void p1_prep(const float* __restrict__ x,
                                               float* __restrict__ xtf,
                                               u16* __restrict__ xth,
                                               u16* __restrict__ xtl,
                                               float* __restrict__ sq) {
    __shared__ float Xp[64][65];
    int tid = threadIdx.x;
    int b = blockIdx.x >> 6;
    int n0 = (blockIdx.x & 63) * 64;
    const float* xb = x + (size_t)b * (CDIM * NPTS);
    int j = tid & 63, cq = tid >> 6;
#pragma unroll
    for (int i = 0; i < 16; i++) {
        int c = cq * 16 + i;
        Xp[c][j] = xb[(size_t)c * NPTS + n0 + j];
    }
    __syncthreads();
    if (tid < 64) {
        float s = 0.f;
        for (int c = 0; c < 64; c++) { float v = Xp[c][tid]; s = fmaf(v, v, s); }
        sq[(size_t)b * NPTS + n0 + tid] = s;
    }
    int n = tid >> 2, c0 = (tid & 3) * 16;
    float vv[16];
#pragma unroll
    for (int i = 0; i < 16; i++) vv[i] = Xp[c0 + i][n];
    size_t rowb = ((size_t)b * NPTS + n0 + n) * 64 + c0;
#pragma unroll
    for (int q = 0; q < 4; q++) {
        float4 f;
        f.x = vv[4 * q]; f.y = vv[4 * q + 1]; f.z = vv[4 * q + 2]; f.w = vv[4 * q + 3];
        *(float4*)(xtf + rowb + 4 * q) = f;
    }
    u16 hb[16], lb[16];
#pragma unroll
    for (int i = 0; i < 16; i++) {
        float v = vv[i];
        u32 bv = __float_as_uint(v);
        u32 h = (bv + 0x7FFFu + ((bv >> 16) & 1u)) >> 16;    // RNE bf16
        float hf = __uint_as_float(h << 16);
        float lf = v - hf;
        u32 bl = __float_as_uint(lf);
        u32 lo = (bl + 0x7FFFu + ((bl >> 16) & 1u)) >> 16;
        hb[i] = (u16)h; lb[i] = (u16)lo;
    }
    uint4 H0, H1, L0, L1;
    H0.x = hb[0] | ((u32)hb[1] << 16);  H0.y = hb[2] | ((u32)hb[3] << 16);
    H0.z = hb[4] | ((u32)hb[5] << 16);  H0.w = hb[6] | ((u32)hb[7] << 16);
    H1.x = hb[8] | ((u32)hb[9] << 16);  H1.y = hb[10] | ((u32)hb[11] << 16);
    H1.z = hb[12] | ((u32)hb[13] << 16); H1.w = hb[14] | ((u32)hb[15] << 16);
    L0.x = lb[0] | ((u32)lb[1] << 16);  L0.y = lb[2] | ((u32)lb[3] << 16);
    L0.z = lb[4] | ((u32)lb[5] << 16);  L0.w = lb[6] | ((u32)lb[7] << 16);
    L1.x = lb[8] | ((u32)lb[9] << 16);  L1.y = lb[10] | ((u32)lb[11] << 16);
    L1.z = lb[12] | ((u32)lb[13] << 16); L1.w = lb[14] | ((u32)lb[15] << 16);
    *(uint4*)(xth + rowb) = H0;
    *(uint4*)(xth + rowb + 8) = H1;
    *(uint4*)(xtl + rowb) = L0;
    *(uint4*)(xtl + rowb + 8) = L1;
}

// ---------------------------------------------------------------------------
// k2: MFMA Gram (Ah*Bh + Al*Bh) over (128 rows x 4096/NCH cols) + per-lane
// register top-16 per col-class; epilogue merges classes -> chunk-top-16 keys.
// Grid 256*NCH; 256 thr (4 waves). NCH=8: 2048 blocks -> 6 blocks/CU (LDS).
// ---------------------------------------------------------------------------
__device__ __forceinline__ void stage_tile(const u16* __restrict__ srcb,
                                           char* lds, int w, int lane) {
#pragma unroll
    for (int i = 0; i < 2; i++) {
        int G = w * 128 + i * 64 + lane;          // 16B granule index in [0,512)
        int rr = G >> 3, gp = G & 7;              // row (gram col), granule-in-row
        const u16* src = srcb + rr * 64 + ((gp ^ (rr & 7)) << 3);
        char* dst = lds + (w * 128 + i * 64) * 16;      // wave-uniform base
        load_lds_16(src, dst);                          // HW adds lane*16
    }
}

__device__ __forceinline__ void sel_phase(const float16v& A, float (*Tw)[36],
                                          float pb, int colbase,
                                          int l31, int lh, u32 (&L)[16]) {
#pragma unroll
    for (int r = 0; r < 16; r++) {
        int row = (r & 3) + 8 * (r >> 2) + 4 * lh;   // m101 C/D row map
        Tw[row][l31] = fmaf(2.f, A[r], pb);          // s + 1024, always > 0
    }
    // same-wave LDS RAW: compiler inserts lgkmcnt waits (validated r3-r8)
    u32 c[16];
    const u32* Tu = (const u32*)&Tw[l31][16 * lh];
#pragma unroll
    for (int q = 0; q < 4; q++) {
        uint4 v = *(const uint4*)(Tu + 4 * q);
        u32 cg = (u32)(colbase + 16 * lh + 4 * q);
        c[4 * q + 0] = (v.x & 0xFFFFF000u) | (cg + 0);
        c[4 * q + 1] = (v.y & 0xFFFFF000u) | (cg + 1);
        c[4 * q + 2] = (v.z & 0xFFFFF000u) | (cg + 2);
        c[4 * q + 3] = (v.w & 0xFFFFF000u) | (cg + 3);
    }
    sort16_desc(c);
    merge_into16(L, c);
}

template <int NCH>
__global__ __launch_bounds__(256, 4) void k2_gram(const u16* __restrict__ xth,
                                                  const u16* __restrict__ xtl,
                                                  const float* __restrict__ sq,
                                                  u32* __restrict__ cand) {
    constexpr int CHCOLS = NPTS / NCH;
    constexpr int TILES = CHCOLS / 64;
    __shared__ char pool[8192];        // B-tile (hi only, XOR-swizzled)
    __shared__ float T[4][32][36];     // per-wave score transpose (18.4 KB)
    int tid = threadIdx.x;
    int lane = tid & 63, w = tid >> 6;
    int l31 = lane & 31, lh = lane >> 5;
    int b = blockIdx.x & 7;                 // batch == XCD slot -> L2 locality
    int rt = (blockIdx.x >> 3) & 31;
    int ch = blockIdx.x >> 8;
    int r0 = rt * 128;
    int cb = ch * CHCOLS;
    size_t bbase = (size_t)b * NPTS;

    // A fragments: rows r0+32w..+31, K=64 in 4 k-steps (hi+lo, regs all run)
    short8v Ah[4], Al[4];
    {
        const u16* pa = xth + (bbase + r0 + 32 * w + l31) * 64 + 8 * lh;
        const u16* pl = xtl + (bbase + r0 + 32 * w + l31) * 64 + 8 * lh;
#pragma unroll
        for (int s = 0; s < 4; s++) {
            Ah[s] = *(const short8v*)(pa + 16 * s);
            Al[s] = *(const short8v*)(pl + 16 * s);
        }
    }

    u32 L[16];
#pragma unroll
    for (int i = 0; i < 16; i++) L[i] = 0u;

    stage_tile(xth + (bbase + cb) * 64, pool, w, lane);
    __syncthreads();                    // vmcnt drained -> tile 0 ready

    float (*Tw)[36] = T[w];

    for (int t = 0; t < TILES; t++) {
        int n1 = cb + t * 64;
        float pb0 = 1024.f - sq[bbase + n1 + l31];
        float pb1 = 1024.f - sq[bbase + n1 + 32 + l31];

        float16v a0 = {};
#pragma unroll
        for (int s = 0; s < 4; s++) {
            int gx = 2 * s + lh;
            int sw = (gx ^ (l31 & 7)) << 4;
            short8v bh0 = *(const short8v*)(pool + l31 * 128 + sw);
            a0 = MFMA32(Ah[s], bh0, a0);    // cols n1+0..31
            a0 = MFMA32(Al[s], bh0, a0);
        }
        sel_phase(a0, Tw, pb0, n1, l31, lh, L);

        float16v a1 = {};
#pragma unroll
        for (int s = 0; s < 4; s++) {
            int gx = 2 * s + lh;
            int sw = (gx ^ (l31 & 7)) << 4;
            short8v bh1 = *(const short8v*)(pool + (32 + l31) * 128 + sw);
            a1 = MFMA32(Ah[s], bh1, a1);    // cols n1+32..63
            a1 = MFMA32(Al[s], bh1, a1);
        }
        __syncthreads();                // all waves done reading pool
        if (t < TILES - 1)
            stage_tile(xth + (bbase + n1 + 64) * 64, pool, w, lane);
        sel_phase(a1, Tw, pb1, n1 + 32, l31, lh, L);   // hides load latency
        __syncthreads();                // drains vmcnt -> next tile ready
    }

    // merge the row's two class-lists -> exact chunk-top-16 (full u32 keys)
    u32 M[16];
#pragma unroll
    for (int i = 0; i < 16; i++) {
        u32 pv = __shfl_xor(L[15 - i], 32);
        M[i] = umaxu(L[i], pv);
    }
#pragma unroll
    for (int j = 8; j >= 1; j >>= 1)
#pragma unroll
        for (int i = 0; i < 16; i++)
            if ((i & j) == 0) {
                int p = i | j;
                u32 a = M[i], b2 = M[p];
                M[i] = umaxu(a, b2);
                M[p] = uminu(a, b2);
            }
    if (lane < 32) {
        u32* cr = cand + (bbase + r0 + 32 * w + l31) * (NCH * 16) + ch * 16;
#pragma unroll
        for (int q = 0; q < 4; q++) {
            uint4 v;
            v.x = M[4 * q]; v.y = M[4 * q + 1]; v.z = M[4 * q + 2]; v.w = M[4 * q + 3];
            *(uint4*)(cr + 4 * q) = v;
        }
    }
}

// ---------------------------------------------------------------------------
// k2b: per row, sort the NCH*16 quantized keys, exact-fp32-rescore top-32,
// then top-20 by u64 key. 8192 blocks x 256 thr; wave = one row.
// NCH=8: 128 keys -> 2/lane double bitonic sort + reversed-max merge (r4).
// ---------------------------------------------------------------------------
template <int NCH>
__global__ __launch_bounds__(256) void k2b_rescore(const float* __restrict__ xtf,
                                                   const float* __restrict__ sq,
                                                   const u32* __restrict__ cand,
                                                   int* __restrict__ knn) {
    __shared__ float xr[4][64];
    __shared__ float dd[4][32];
    __shared__ u32 cols[4][32];
    int tid = threadIdx.x;
    int lane = tid & 63, w = tid >> 6;
    int bid = blockIdx.x;
    size_t sb = (size_t)((bid & 7) * 1024 + (bid >> 3));   // batch = XCD slot
    size_t row = sb * 4 + w;
    size_t bbase = (row >> 12) << 12;

    if (lane < 16)
        *(float4*)&xr[w][lane * 4] = *(const float4*)(xtf + row * 64 + lane * 4);

    u32 top;   // this lane's slot in the sorted-desc union (lane i = i-th best)
    if (NCH == 4) {
        u32 key = cand[row * 64 + lane];
#pragma unroll
        for (u32 k = 2; k <= 64; k <<= 1) {
#pragma unroll
            for (u32 j2 = k >> 1; j2 >= 1; j2 >>= 1) {
                bool up = ((lane & k) == 0);
                bool lower = ((lane & j2) == 0);
                u32 p = __shfl_xor(key, j2);
                u32 mx = (key > p) ? key : p, mn = (key > p) ? p : key;
                key = (lower == up) ? mx : mn;
            }
        }
        top = key;
    } else {
        u32 kA = cand[row * 128 + lane];
        u32 kB = cand[row * 128 + 64 + lane];
#pragma unroll
        for (u32 k = 2; k <= 64; k <<= 1) {
#pragma unroll
            for (u32 j2 = k >> 1; j2 >= 1; j2 >>= 1) {
                bool up = ((lane & k) == 0);
                bool lower = ((lane & j2) == 0);
                u32 pA = __shfl_xor(kA, j2);
                u32 mxA = (kA > pA) ? kA : pA, mnA = (kA > pA) ? pA : kA;
                kA = (lower == up) ? mxA : mnA;
                u32 pB = __shfl_xor(kB, j2);
                u32 mxB = (kB > pB) ? kB : pB, mnB = (kB > pB) ? pB : kB;
                kB = (lower == up) ? mxB : mnB;
            }
        }
        u32 rB = __shfl(kB, 63 - lane);
        u32 M = umaxu(kA, rB);          // top-64 of 128, bitonic
#pragma unroll
        for (u32 j2 = 32; j2 >= 1; j2 >>= 1) {
            u32 p = __shfl_xor(M, j2);
            bool lower = ((lane & j2) == 0);
            M = lower ? umaxu(M, p) : uminu(M, p);
        }
        top = M;
    }
    if (lane < 32) cols[w][lane] = top & 0xFFFu;   // top-32 candidates' cols

    // cooperative exact rescore: 2 passes x 16 candidates, 4 lanes each
    int s = lane & 3, g = lane >> 2;
    float4 xq[4];
#pragma unroll
    for (int q = 0; q < 4; q++) xq[q] = *(const float4*)&xr[w][16 * q + 4 * s];

#pragma unroll
    for (int p = 0; p < 2; p++) {
        int m = cols[w][p * 16 + g];
        const float* pm = xtf + (bbase + m) * 64;
        float d = 0.f;
#pragma unroll
        for (int q = 0; q < 4; q++) {
            float4 v = *(const float4*)(pm + 16 * q + 4 * s);
            d = fmaf(v.x, xq[q].x, d); d = fmaf(v.y, xq[q].y, d);
            d = fmaf(v.z, xq[q].z, d); d = fmaf(v.w, xq[q].w, d);
        }
        d += __shfl_xor(d, 1);
        d += __shfl_xor(d, 2);
        if (s == 0) dd[w][p * 16 + g] = d;
    }

    // exact u64 keys (fp32 score + lowest-index tie-break), lanes 0..31
    u64 kE = 0;
    if (lane < 32) {
        int m = (int)cols[w][lane];
        float sE = fmaf(2.f, dd[w][lane], -sq[bbase + m]);
        kE = ((u64)ordf(sE) << 32) | (u32)(~(u32)m);
    }
#pragma unroll
    for (u32 k = 2; k <= 64; k <<= 1) {
#pragma unroll
        for (u32 j2 = k >> 1; j2 >= 1; j2 >>= 1) {
            bool up = ((lane & k) == 0);
            bool lower = ((lane & j2) == 0);
            u64 p = __shfl_xor(kE, j2);
            u64 mx = (kE > p) ? kE : p, mn = (kE > p) ? p : kE;
            kE = (lower == up) ? mx : mn;
        }
    }
    if (lane < KSEL)
        knn[row * KSEL + lane] = (int)(~(u32)kE);
}

// ---------------------------------------------------------------------------
// k1: y1[n][o] = sum_c x[b][c][n]*Wt[c][o] (o'<64); y2: o'>=64. (validated)
// ---------------------------------------------------------------------------
__global__ __launch_bounds__(256) void k1_prep(const float* __restrict__ x,
                                               const float* __restrict__ Wtg,
                                               float* __restrict__ y1,
                                               float* __restrict__ y2) {
    __shared__ float Xt[64][128];
    __shared__ float Wt[64][128];
    int tid = threadIdx.x;
    int gr0 = blockIdx.x * 128;
    int b = gr0 >> 12;
    int n0 = gr0 & 4095;
    const float* xb = x + (size_t)b * (CDIM * NPTS) + n0;

    for (int k = 0; k < 32; k++) {
        int f = tid + 256 * k;
        int c = f >> 7, j = f & 127;
        Xt[c][j] = xb[(size_t)c * NPTS + j];
        ((float*)Wt)[f] = Wtg[f];
    }
    __syncthreads();

    int tr = tid & 15, tc = tid >> 4;
    float acc[8][8];
#pragma unroll
    for (int i = 0; i < 8; i++)
#pragma unroll
        for (int j = 0; j < 8; j++) acc[i][j] = 0.f;

#pragma unroll 4
    for (int c = 0; c < 64; c++) {
        float a[8], bb[8];
        *(float4*)&a[0]  = *(const float4*)&Xt[c][8 * tr];
        *(float4*)&a[4]  = *(const float4*)&Xt[c][8 * tr + 4];
        *(float4*)&bb[0] = *(const float4*)&Wt[c][8 * tc];
        *(float4*)&bb[4] = *(const float4*)&Wt[c][8 * tc + 4];
#pragma unroll
        for (int i = 0; i < 8; i++)
#pragma unroll
            for (int j = 0; j < 8; j++) acc[i][j] = fmaf(a[i], bb[j], acc[i][j]);
    }

#pragma unroll
    for (int i = 0; i < 8; i++) {
        int r = gr0 + 8 * tr + i;
        float* dst = (tc < 8) ? (y1 + (size_t)r * 64 + 8 * tc)
                              : (y2 + (size_t)r * 64 + (8 * tc - 64));
        float4 s0, s1;
        s0.x = acc[i][0]; s0.y = acc[i][1]; s0.z = acc[i][2]; s0.w = acc[i][3];
        s1.x = acc[i][4]; s1.y = acc[i][5]; s1.z = acc[i][6]; s1.w = acc[i][7];
        *(float4*)dst = s0;
        *(float4*)(dst + 4) = s1;
    }
}

// ---------------------------------------------------------------------------
// k3: out[b][o][n] = max_k y1[b][idx[n][k]][o] + y2[b][n][o] + bias[o]
// 1024 blocks (b x 128 tiles of 32 rows) for 4 blocks/CU latency hiding.
// ---------------------------------------------------------------------------
__global__ __launch_bounds__(256) void k3_out(const float* __restrict__ y1,
                                              const float* __restrict__ y2,
                                              const int* __restrict__ knn,
                                              const float* __restrict__ bias,
                                              float* __restrict__ out) {
    __shared__ float outT[64][33];   // [o][n-local], +1 pad
    __shared__ int idxT[32 * KSEL];
    int tid = threadIdx.x;
    int b = blockIdx.x & 7;
    int n0 = (blockIdx.x >> 3) * 32;

    for (int f = tid; f < 32 * KSEL; f += 256)
        idxT[f] = knn[((size_t)b * NPTS + n0) * KSEL + f];
    __syncthreads();

    int lane = tid & 63, w = tid >> 6;
    float bl = bias[lane];
    const float* y1b = y1 + (size_t)b * NPTS * 64;

    for (int i = 0; i < 8; i++) {
        int rr = w * 8 + i;
        float acc = -FLT_MAX;
#pragma unroll
        for (int k = 0; k < KSEL; k++) {
            int m = idxT[rr * KSEL + k];
            acc = fmaxf(acc, y1b[(size_t)m * 64 + lane]);
        }
        acc = acc + y2[((size_t)b * NPTS + n0 + rr) * 64 + lane] + bl;
        outT[lane][rr] = acc;
    }
    __syncthreads();

    int j = tid & 31, og = tid >> 5;
    for (int it = 0; it < 8; it++) {
        int o = it * 8 + og;
        out[((size_t)(b * 64 + o)) * NPTS + n0 + j] = outT[o][j];
    }
}

// ---------------------------------------------------------------------------
extern "C" void kernel_launch(void* const* d_in, const int* in_sizes, int n_in,
                              void* d_out, int out_size, void* d_ws, size_t ws_size,
                              hipStream_t stream) {
    const float* x    = (const float*)d_in[0];   // (8, 64, 4096)
    const float* W    = (const float*)d_in[1];   // (64, 128)
    const float* bias = (const float*)d_in[2];   // (64,)
    float* out = (float*)d_out;                  // (8, 64, 4096)
    float* ws = (float*)d_ws;

    bool big = ws_size >= B_NEED_BYTES;          // deterministic per process

    u16* xth   = (u16*)ws;                  // [0,4MB)   dies before k1
    u16* xtl   = (u16*)(ws + OFF_XTL);      // [4,8MB)   dies before k1
    u32* candb = (u32*)(ws + OFF_Y2);       // [8,16/24MB) keys; dies before k1/y2 use
    float* y1  = ws + OFF_Y1;
    float* y2  = ws + OFF_Y2;
    float* sq  = ws + (big ? B_OFF_SQ : S_OFF_SQ);
    float* Wt  = ws + (big ? B_OFF_WT : S_OFF_WT);
    int* knn   = (int*)(ws + (big ? B_OFF_KNN : S_OFF_KNN));
    float* xtf = (float*)d_out;             // fp32 transposed copy; k3 overwrites

    hipLaunchKernelGGL(k0_wt,   dim3(32),  dim3(256), 0, stream, W, Wt);
    hipLaunchKernelGGL(p1_prep, dim3(512), dim3(256), 0, stream, x, xtf, xth, xtl, sq);
    if (big) {
        hipLaunchKernelGGL((k2_gram<8>),     dim3(2048), dim3(256), 0, stream, xth, xtl, sq, candb);
        hipLaunchKernelGGL((k2b_rescore<8>), dim3(8192), dim3(256), 0, stream, xtf, sq, candb, knn);
    } else {
        hipLaunchKernelGGL((k2_gram<4>),     dim3(1024), dim3(256), 0, stream, xth, xtl, sq, candb);
        hipLaunchKernelGGL((k2b_rescore<4>), dim3(8192), dim3(256), 0, stream, xtf, sq, candb, knn);
    }
    hipLaunchKernelGGL(k1_prep, dim3(256),  dim3(256), 0, stream, x, Wt, y1, y2);
    hipLaunchKernelGGL(k3_out,  dim3(1024), dim3(256), 0, stream, y1, y2, knn, bias, out);
}